// Round 2
// baseline (13054.202 us; speedup 1.0000x reference)
//
#include <hip/hip_runtime.h>
#include <hip/hip_bf16.h>

// Model dims
#define BB 64
#define TT 512
#define DD 512
#define EE 6
#define PP 96
#define NHH 4
#define HDD 128
#define FFF 2048

typedef short bf16x8 __attribute__((ext_vector_type(8)));
typedef float f32x4 __attribute__((ext_vector_type(4)));

__device__ __forceinline__ float bf2f(unsigned short u) {
    unsigned int x = ((unsigned int)u) << 16;
    return __uint_as_float(x);
}
__device__ __forceinline__ unsigned short f2bf(float f) {
    __hip_bfloat16 h = __float2bfloat16(f);
    return *reinterpret_cast<unsigned short*>(&h);
}

// ---------------------------------------------------------------------------
// Generic MFMA GEMM:  C[m][n] = alpha * sum_k A[m][k] * W[n][k]  (+bias[n])
// A, W bf16 (as ushort). 128x128 block tile, BK=32, 256 threads (4 waves,
// each wave a 64x64 quadrant = 4x4 mfma_f32_16x16x32_bf16 tiles).
// TRANSW: W accessed as W[k*ldw + n] (stages V^T for the P·V gemm).
// Batched via blockIdx.z: z -> (b = z/Hdiv, h = z%Hdiv) offsets.
// ---------------------------------------------------------------------------
template<bool TRANSW, bool BIAS, bool RELU, bool OUTBF16>
__global__ __launch_bounds__(256) void gemm_bt(
    const unsigned short* __restrict__ A, int lda, long long aB, long long aH,
    const unsigned short* __restrict__ W, int ldw, long long wB, long long wH,
    const float* __restrict__ bias,
    void* __restrict__ Cv, int ldc, long long cB, long long cH,
    int K, int Hdiv, float alpha)
{
    __shared__ unsigned short As[128 * 40];
    __shared__ unsigned short Ws[128 * 40];
    int t = threadIdx.x;
    int z = blockIdx.z;
    int zb = z / Hdiv, zh = z - zb * Hdiv;
    long long aOff = (long long)zb * aB + (long long)zh * aH;
    long long wOff = (long long)zb * wB + (long long)zh * wH;
    long long cOff = (long long)zb * cB + (long long)zh * cH;
    int m0 = blockIdx.x * 128, n0 = blockIdx.y * 128;

    int arow = t >> 1, acol = (t & 1) * 16;
    const unsigned short* Ag = A + aOff + (long long)(m0 + arow) * lda + acol;
    const unsigned short* WgN = W + wOff + (long long)(n0 + arow) * ldw + acol;
    int wk = t >> 3, wn = (t & 7) * 16;
    const unsigned short* WgT = W + wOff + n0 + wn;

    int wave = t >> 6, lane = t & 63;
    int wm = (wave & 1) * 64, wn2 = (wave >> 1) * 64;
    int lrow = lane & 15, quad = lane >> 4;

    f32x4 acc[4][4];
    #pragma unroll
    for (int i = 0; i < 4; i++)
        #pragma unroll
        for (int j = 0; j < 4; j++)
            acc[i][j] = (f32x4){0.f, 0.f, 0.f, 0.f};

    for (int k0 = 0; k0 < K; k0 += 32) {
        __syncthreads();
        {
            uint4 a0 = *(const uint4*)(Ag + k0);
            uint4 a1 = *(const uint4*)(Ag + k0 + 8);
            *(uint4*)&As[arow * 40 + acol] = a0;
            *(uint4*)&As[arow * 40 + acol + 8] = a1;
            if (!TRANSW) {
                uint4 w0 = *(const uint4*)(WgN + k0);
                uint4 w1 = *(const uint4*)(WgN + k0 + 8);
                *(uint4*)&Ws[arow * 40 + acol] = w0;
                *(uint4*)&Ws[arow * 40 + acol + 8] = w1;
            } else {
                const unsigned short* p = WgT + (long long)(k0 + wk) * ldw;
                uint4 w0 = *(const uint4*)(p);
                uint4 w1 = *(const uint4*)(p + 8);
                const unsigned short* s0 = (const unsigned short*)&w0;
                const unsigned short* s1 = (const unsigned short*)&w1;
                #pragma unroll
                for (int j = 0; j < 8; j++) Ws[(wn + j) * 40 + wk] = s0[j];
                #pragma unroll
                for (int j = 0; j < 8; j++) Ws[(wn + 8 + j) * 40 + wk] = s1[j];
            }
        }
        __syncthreads();
        bf16x8 af[4], bf[4];
        #pragma unroll
        for (int i = 0; i < 4; i++)
            af[i] = *(const bf16x8*)&As[(wm + i * 16 + lrow) * 40 + quad * 8];
        #pragma unroll
        for (int j = 0; j < 4; j++)
            bf[j] = *(const bf16x8*)&Ws[(wn2 + j * 16 + lrow) * 40 + quad * 8];
        #pragma unroll
        for (int i = 0; i < 4; i++)
            #pragma unroll
            for (int j = 0; j < 4; j++)
                acc[i][j] = __builtin_amdgcn_mfma_f32_16x16x32_bf16(af[i], bf[j], acc[i][j], 0, 0, 0);
    }

    #pragma unroll
    for (int i = 0; i < 4; i++) {
        #pragma unroll
        for (int j = 0; j < 4; j++) {
            #pragma unroll
            for (int r = 0; r < 4; r++) {
                int row = m0 + wm + i * 16 + quad * 4 + r;
                int col = n0 + wn2 + j * 16 + lrow;
                float v = acc[i][j][r] * alpha;
                if (BIAS) v += bias[col];
                if (RELU) v = fmaxf(v, 0.f);
                long long idx = cOff + (long long)row * ldc + col;
                if (OUTBF16) ((unsigned short*)Cv)[idx] = f2bf(v);
                else         ((float*)Cv)[idx] = v;
            }
        }
    }
}

// ---------------------------------------------------------------------------
__global__ void cvt_k(const float* __restrict__ in, unsigned short* __restrict__ out, int n)
{
    int i = blockIdx.x * 256 + threadIdx.x;
    int stride = gridDim.x * 256;
    for (; i < n; i += stride) out[i] = f2bf(in[i]);
}

// ---------------------------------------------------------------------------
// GARCH: per-batch variance + 511-step scalar recurrence. 1 block, lane = batch.
// ---------------------------------------------------------------------------
__global__ __launch_bounds__(64) void garch_k(
    const float* __restrict__ xe, const float* __restrict__ omega,
    const float* __restrict__ alpha, const float* __restrict__ beta,
    float* __restrict__ vol)
{
    int b = threadIdx.x;
    float sm = 0.f, sq = 0.f;
    for (int t2 = 0; t2 < TT; t2++) {
        float r = xe[((long long)b * TT + t2) * EE + 5];
        sm += r; sq += r * r;
    }
    float mean = sm / 512.f;
    float var = (sq - 512.f * mean * mean) / 511.f;
    float h = var + 1e-6f;
    float om = log1pf(expf(omega[0]));
    float al = 0.2f / (1.f + expf(-alpha[0]));
    float be = 0.8f / (1.f + expf(-beta[0]));
    for (int t2 = 0; t2 < TT - 1; t2++) {
        float r = xe[((long long)b * TT + t2) * EE + 5];
        h = om + al * r * r + be * h;
    }
    vol[b] = sqrtf(h);
}

// ---------------------------------------------------------------------------
// LSTM step: grid 512 (one hidden dim per block), 64 threads (lane = batch).
// ---------------------------------------------------------------------------
__global__ __launch_bounds__(64) void lstm_step_k(
    const float* __restrict__ xe, const float* __restrict__ w_hh,
    const float* __restrict__ w_ih, const float* __restrict__ b_ih,
    const float* __restrict__ b_hh,
    const float* __restrict__ hin, float* __restrict__ hout,
    float* __restrict__ cT, float* __restrict__ xT, int t)
{
    int d = blockIdx.x, lane = threadIdx.x;
    const float* w0 = w_hh + (long long)d * 512;
    const float* w1 = w_hh + (long long)(512 + d) * 512;
    const float* w2 = w_hh + (long long)(1024 + d) * 512;
    const float* w3 = w_hh + (long long)(1536 + d) * 512;
    float a0 = 0.f, a1 = 0.f, a2 = 0.f, a3 = 0.f;
    #pragma unroll 8
    for (int k = 0; k < 512; k++) {
        float hv = hin[k * 64 + lane];
        a0 += hv * w0[k]; a1 += hv * w1[k]; a2 += hv * w2[k]; a3 += hv * w3[k];
    }
    const float* xr = xe + ((long long)lane * TT + t) * EE;
    float x0 = xr[0], x1 = xr[1], x2 = xr[2], x3 = xr[3], x4 = xr[4], x5 = xr[5];
#define XDOT(r_) (x0*w_ih[(r_)*6+0] + x1*w_ih[(r_)*6+1] + x2*w_ih[(r_)*6+2] + \
                  x3*w_ih[(r_)*6+3] + x4*w_ih[(r_)*6+4] + x5*w_ih[(r_)*6+5])
    float pi = a0 + XDOT(d)        + b_ih[d]        + b_hh[d];
    float pf = a1 + XDOT(512 + d)  + b_ih[512 + d]  + b_hh[512 + d];
    float pg = a2 + XDOT(1024 + d) + b_ih[1024 + d] + b_hh[1024 + d];
    float po = a3 + XDOT(1536 + d) + b_ih[1536 + d] + b_hh[1536 + d];
#undef XDOT
    float ig = 1.f / (1.f + expf(-pi));
    float fg = 1.f / (1.f + expf(-pf));
    float gg = tanhf(pg);
    float og = 1.f / (1.f + expf(-po));
    float c = cT[d * 64 + lane];
    float cn = fg * c + ig * gg;
    float hn = og * tanhf(cn);
    cT[d * 64 + lane] = cn;
    hout[d * 64 + lane] = hn;
    xT[((long long)t * 512 + d) * 64 + lane] = hn;
}

// ---------------------------------------------------------------------------
// Transpose xT[t][d][b] -> XB[b][t][d] bf16
// ---------------------------------------------------------------------------
__global__ __launch_bounds__(256) void transpose_k(
    const float* __restrict__ xT, unsigned short* __restrict__ XB_)
{
    __shared__ float tile[64][65];
    int dc = blockIdx.x, t = blockIdx.y;
    int tid = threadIdx.x;
    int bcol = tid & 63, grp = tid >> 6;
    #pragma unroll
    for (int j = 0; j < 16; j++) {
        int i = grp * 16 + j;
        tile[i][bcol] = xT[((long long)t * 512 + dc * 64 + i) * 64 + bcol];
    }
    __syncthreads();
    #pragma unroll
    for (int j = 0; j < 16; j++) {
        int brow = grp * 16 + j;
        float v = tile[bcol][brow];
        long long idx = ((long long)brow * TT + t) * DD + dc * 64 + bcol;
        XB_[idx] = f2bf(v);
    }
}

// ---------------------------------------------------------------------------
// Softmax over last dim (512), in-place on bf16 scores. One wave per row.
// ---------------------------------------------------------------------------
__global__ __launch_bounds__(256) void softmax_k(unsigned short* __restrict__ S)
{
    long long row = (long long)blockIdx.x * 4 + (threadIdx.x >> 6);
    int lane = threadIdx.x & 63;
    unsigned short* p = S + row * 512 + lane * 8;
    uint4 raw = *(const uint4*)p;
    unsigned short* u = (unsigned short*)&raw;
    float v[8];
    float m = -1e30f;
    #pragma unroll
    for (int j = 0; j < 8; j++) { v[j] = bf2f(u[j]); m = fmaxf(m, v[j]); }
    #pragma unroll
    for (int off = 1; off < 64; off <<= 1) m = fmaxf(m, __shfl_xor(m, off));
    float s = 0.f;
    #pragma unroll
    for (int j = 0; j < 8; j++) { v[j] = __expf(v[j] - m); s += v[j]; }
    #pragma unroll
    for (int off = 1; off < 64; off <<= 1) s += __shfl_xor(s, off);
    float inv = 1.f / s;
    unsigned int pk[4];
    #pragma unroll
    for (int j = 0; j < 4; j++)
        pk[j] = (unsigned int)f2bf(v[2 * j] * inv) | ((unsigned int)f2bf(v[2 * j + 1] * inv) << 16);
    *(uint4*)p = make_uint4(pk[0], pk[1], pk[2], pk[3]);
}

// ---------------------------------------------------------------------------
// Residual + LayerNorm: XB = LN(XB + Y)*g + b  (bf16 residual stream).
// One wave per row of 512.
// ---------------------------------------------------------------------------
__global__ __launch_bounds__(256) void ln_k(
    unsigned short* XB_, const float* __restrict__ Y_,
    const float* __restrict__ g, const float* __restrict__ b2)
{
    long long row = (long long)blockIdx.x * 4 + (threadIdx.x >> 6);
    int lane = threadIdx.x & 63;
    long long base = row * 512 + lane * 8;
    float s[8];
    {
        uint4 xr = *(const uint4*)&XB_[base];
        const unsigned short* xu = (const unsigned short*)&xr;
        float4 y0 = *(const float4*)&Y_[base];
        float4 y1 = *(const float4*)&Y_[base + 4];
        s[0] = bf2f(xu[0]) + y0.x; s[1] = bf2f(xu[1]) + y0.y;
        s[2] = bf2f(xu[2]) + y0.z; s[3] = bf2f(xu[3]) + y0.w;
        s[4] = bf2f(xu[4]) + y1.x; s[5] = bf2f(xu[5]) + y1.y;
        s[6] = bf2f(xu[6]) + y1.z; s[7] = bf2f(xu[7]) + y1.w;
    }
    float sm = 0.f, sq = 0.f;
    #pragma unroll
    for (int j = 0; j < 8; j++) { sm += s[j]; sq += s[j] * s[j]; }
    #pragma unroll
    for (int off = 1; off < 64; off <<= 1) {
        sm += __shfl_xor(sm, off);
        sq += __shfl_xor(sq, off);
    }
    float mean = sm * (1.f / 512.f);
    float var = sq * (1.f / 512.f) - mean * mean;
    float rstd = rsqrtf(var + 1e-5f);
    int col = lane * 8;
    float o[8];
    #pragma unroll
    for (int j = 0; j < 8; j++) o[j] = (s[j] - mean) * rstd * g[col + j] + b2[col + j];
    unsigned int pk[4];
    #pragma unroll
    for (int j = 0; j < 4; j++)
        pk[j] = (unsigned int)f2bf(o[2 * j]) | ((unsigned int)f2bf(o[2 * j + 1]) << 16);
    *(uint4*)&XB_[base] = make_uint4(pk[0], pk[1], pk[2], pk[3]);
}

// ---------------------------------------------------------------------------
// Heads: garch_base + gate * ai_residual. One block per batch.
// ---------------------------------------------------------------------------
__global__ __launch_bounds__(128) void head_k(
    const unsigned short* __restrict__ XB_, const float* __restrict__ xe,
    const float* __restrict__ vol,
    const float* __restrict__ rh_w, const float* __restrict__ rh_b,
    const float* __restrict__ g1_w, const float* __restrict__ g1_b,
    const float* __restrict__ g2_w, const float* __restrict__ g2_b,
    const float* __restrict__ gp_w, const float* __restrict__ gp_b,
    float* __restrict__ out)
{
    int b = blockIdx.x, t = threadIdx.x;
    __shared__ float xl[512];
    __shared__ float hid[256];
    for (int j = t; j < 512; j += 128)
        xl[j] = bf2f(XB_[((long long)b * TT + (TT - 1)) * DD + j]);
    float gin[7];
    #pragma unroll
    for (int e = 0; e < 6; e++) gin[e] = xe[((long long)b * TT + (TT - 1)) * EE + e];
    gin[6] = vol[b];
    for (int j = t; j < 256; j += 128) {
        float s = g1_b[j];
        #pragma unroll
        for (int e = 0; e < 7; e++) s += g1_w[j * 7 + e] * gin[e];
        hid[j] = fmaxf(s, 0.f);
    }
    __syncthreads();
    for (int p = t; p < 96; p += 128) {
        float ai = rh_b[p];
        for (int j = 0; j < 512; j++) ai += xl[j] * rh_w[p * 512 + j];
        float gs = g2_b[p];
        for (int j = 0; j < 256; j++) gs += hid[j] * g2_w[p * 256 + j];
        float gate = 1.f / (1.f + expf(-gs));
        out[b * PP + p] = vol[b] * gp_w[p] + gp_b[p] + gate * ai;
    }
}

// ---------------------------------------------------------------------------
// Launch.  Workspace layout (bytes, total ~147.2 MB):
//   XB   bf16 residual  @ 0           (33554432)
//   Y    fp32 branch    @ 33554432    (67108864)   [aliases LSTM xT]
//   CH   chunk region   @ 100663296   (33554432)
//        QKVc bf16 @ +0 (12582912) | SCc @ +12582912 (16777216) | CTXc @ +29360128 (4194304)
//        HIDc bf16 @ +0 (33554432)  [FFN phase]
//   WB   bf16 weights   @ 134217728   (12582912)
//   HT0/HT1/CT          @ 146800640   (3 x 131072)
//   VOL                 @ 147193856
// ---------------------------------------------------------------------------
extern "C" void kernel_launch(void* const* d_in, const int* in_sizes, int n_in,
                              void* d_out, int out_size, void* d_ws, size_t ws_size,
                              hipStream_t stream)
{
    const float* x_enc      = (const float*)d_in[0];
    const float* omega      = (const float*)d_in[4];
    const float* alpha      = (const float*)d_in[5];
    const float* beta       = (const float*)d_in[6];
    const float* gp_w       = (const float*)d_in[7];
    const float* gp_b       = (const float*)d_in[8];
    const float* w_ih       = (const float*)d_in[9];
    const float* w_hh       = (const float*)d_in[10];
    const float* b_ih       = (const float*)d_in[11];
    const float* b_hh       = (const float*)d_in[12];
    const float* attn_in_w  = (const float*)d_in[13];
    const float* attn_in_b  = (const float*)d_in[14];
    const float* attn_out_w = (const float*)d_in[15];
    const float* attn_out_b = (const float*)d_in[16];
    const float* ln1_g      = (const float*)d_in[17];
    const float* ln1_b      = (const float*)d_in[18];
    const float* ffn_w1     = (const float*)d_in[19];
    const float* ffn_b1     = (const float*)d_in[20];
    const float* ffn_w2     = (const float*)d_in[21];
    const float* ffn_b2     = (const float*)d_in[22];
    const float* ln2_g      = (const float*)d_in[23];
    const float* ln2_b      = (const float*)d_in[24];
    const float* rh_w       = (const float*)d_in[25];
    const float* rh_b       = (const float*)d_in[26];
    const float* g1_w       = (const float*)d_in[27];
    const float* g1_b       = (const float*)d_in[28];
    const float* g2_w       = (const float*)d_in[29];
    const float* g2_b       = (const float*)d_in[30];

    char* ws = (char*)d_ws;
    unsigned short* XB   = (unsigned short*)(ws + 0);
    float*          Y    = (float*)(ws + 33554432LL);
    float*          XT   = Y;
    unsigned short* QKVc = (unsigned short*)(ws + 100663296LL);
    unsigned short* SCc  = (unsigned short*)(ws + 113246208LL);
    unsigned short* CTXc = (unsigned short*)(ws + 130023424LL);
    unsigned short* HIDc = (unsigned short*)(ws + 100663296LL);
    unsigned short* WATI = (unsigned short*)(ws + 134217728LL);
    unsigned short* WATO = WATI + 1572864;
    unsigned short* WF1  = WATI + 2097152;
    unsigned short* WF2  = WATI + 4194304;
    float*          HT0  = (float*)(ws + 146800640LL);
    float*          HT1  = (float*)(ws + 146931712LL);
    float*          CT   = (float*)(ws + 147062784LL);
    float*          VOL  = (float*)(ws + 147193856LL);

    hipMemsetAsync(HT0, 0, 131072, stream);
    hipMemsetAsync(CT, 0, 131072, stream);

    cvt_k<<<2048, 256, 0, stream>>>(attn_in_w,  WATI, 1572864);
    cvt_k<<<1024, 256, 0, stream>>>(attn_out_w, WATO, 524288);
    cvt_k<<<2048, 256, 0, stream>>>(ffn_w1,     WF1,  2097152);
    cvt_k<<<2048, 256, 0, stream>>>(ffn_w2,     WF2,  2097152);

    garch_k<<<1, 64, 0, stream>>>(x_enc, omega, alpha, beta, VOL);

    for (int t = 0; t < 512; t++) {
        const float* hin = (t & 1) ? HT1 : HT0;
        float* hout      = (t & 1) ? HT0 : HT1;
        lstm_step_k<<<512, 64, 0, stream>>>(x_enc, w_hh, w_ih, b_ih, b_hh,
                                            hin, hout, CT, XT, t);
    }
    transpose_k<<<dim3(8, 512, 1), 256, 0, stream>>>(XT, XB);

    for (int l = 0; l < 2; l++) {
        // Attention, chunked over batches: 8 chunks x 8 batches (4096 rows)
        for (int c = 0; c < 8; c++) {
            long long rowOff = (long long)c * 8 * 512;
            // QKV projection for this chunk -> QKVc (4096 x 1536 bf16)
            gemm_bt<false, true, false, true><<<dim3(32, 12, 1), 256, 0, stream>>>(
                XB + rowOff * 512, 512, 0, 0,
                WATI + l * 786432, 512, 0, 0, attn_in_b + l * 1536,
                QKVc, 1536, 0, 0, 512, 1, 1.0f);
            // scores = Q K^T / sqrt(128), z over 8 batches x 4 heads
            gemm_bt<false, false, false, true><<<dim3(4, 4, 32), 256, 0, stream>>>(
                QKVc, 1536, 786432LL, 128LL, QKVc + 512, 1536, 786432LL, 128LL, nullptr,
                SCc, 512, 1048576LL, 262144LL, 128, 4, 0.088388347648318447f);
            softmax_k<<<4096, 256, 0, stream>>>(SCc);
            // ctx = P V (V staged transposed) -> CTXc (b,t,d layout, 4096 x 512)
            gemm_bt<true, false, false, true><<<dim3(4, 1, 32), 256, 0, stream>>>(
                SCc, 512, 1048576LL, 262144LL, QKVc + 1024, 1536, 786432LL, 128LL, nullptr,
                CTXc, 512, 262144LL, 128LL, 512, 4, 1.0f);
            // attn out projection -> fp32 Y rows of this chunk
            gemm_bt<false, true, false, false><<<dim3(32, 4, 1), 256, 0, stream>>>(
                CTXc, 512, 0, 0, WATO + l * 262144, 512, 0, 0, attn_out_b + l * 512,
                Y + rowOff * 512, 512, 0, 0, 512, 1, 1.0f);
        }
        ln_k<<<8192, 256, 0, stream>>>(XB, Y, ln1_g + l * 512, ln1_b + l * 512);

        // FFN, chunked over rows: 4 chunks x 8192 rows
        for (int mc = 0; mc < 4; mc++) {
            long long rowOff = (long long)mc * 8192;
            gemm_bt<false, true, true, true><<<dim3(64, 16, 1), 256, 0, stream>>>(
                XB + rowOff * 512, 512, 0, 0,
                WF1 + l * 1048576, 512, 0, 0, ffn_b1 + l * 2048,
                HIDc, 2048, 0, 0, 512, 1, 1.0f);
            gemm_bt<false, true, false, false><<<dim3(64, 4, 1), 256, 0, stream>>>(
                HIDc, 2048, 0, 0, WF2 + l * 1048576, 2048, 0, 0, ffn_b2 + l * 512,
                Y + rowOff * 512, 512, 0, 0, 2048, 1, 1.0f);
        }
        ln_k<<<8192, 256, 0, stream>>>(XB, Y, ln2_g + l * 512, ln2_b + l * 512);
    }

    head_k<<<64, 128, 0, stream>>>(XB, x_enc, VOL, rh_w, rh_b,
                                   g1_w, g1_b, g2_w, g2_b, gp_w, gp_b,
                                   (float*)d_out);
}

// Round 4
// 9527.184 us; speedup vs baseline: 1.3702x; 1.3702x over previous
//
#include <hip/hip_runtime.h>
#include <hip/hip_bf16.h>

// Model dims
#define BB 64
#define TT 512
#define DD 512
#define EE 6
#define PP 96
#define NHH 4
#define HDD 128
#define FFF 2048

typedef short bf16x8 __attribute__((ext_vector_type(8)));
typedef float f32x4 __attribute__((ext_vector_type(4)));

__device__ __forceinline__ float bf2f(unsigned short u) {
    unsigned int x = ((unsigned int)u) << 16;
    return __uint_as_float(x);
}
__device__ __forceinline__ unsigned short f2bf(float f) {
    __hip_bfloat16 h = __float2bfloat16(f);
    return *reinterpret_cast<unsigned short*>(&h);
}

// ---------------------------------------------------------------------------
// Generic MFMA GEMM:  C[m][n] = alpha * sum_k A[m][k] * W[n][k]  (+bias[n])
// 128x128 tile, BK=32, 256 threads (4 waves, each a 64x64 quadrant of
// 4x4 mfma_f32_16x16x32_bf16). TRANSW stages W[k*ldw+n] (V^T for P·V).
// Batched via blockIdx.z -> (b = z/Hdiv, h = z%Hdiv) offsets.
// ---------------------------------------------------------------------------
template<bool TRANSW, bool BIAS, bool RELU, bool OUTBF16>
__global__ __launch_bounds__(256) void gemm_bt(
    const unsigned short* __restrict__ A, int lda, long long aB, long long aH,
    const unsigned short* __restrict__ W, int ldw, long long wB, long long wH,
    const float* __restrict__ bias,
    void* __restrict__ Cv, int ldc, long long cB, long long cH,
    int K, int Hdiv, float alpha)
{
    __shared__ unsigned short As[128 * 40];
    __shared__ unsigned short Ws[128 * 40];
    int t = threadIdx.x;
    int z = blockIdx.z;
    int zb = z / Hdiv, zh = z - zb * Hdiv;
    long long aOff = (long long)zb * aB + (long long)zh * aH;
    long long wOff = (long long)zb * wB + (long long)zh * wH;
    long long cOff = (long long)zb * cB + (long long)zh * cH;
    int m0 = blockIdx.x * 128, n0 = blockIdx.y * 128;

    int arow = t >> 1, acol = (t & 1) * 16;
    const unsigned short* Ag = A + aOff + (long long)(m0 + arow) * lda + acol;
    const unsigned short* WgN = W + wOff + (long long)(n0 + arow) * ldw + acol;
    int wk = t >> 3, wn = (t & 7) * 16;
    const unsigned short* WgT = W + wOff + n0 + wn;

    int wave = t >> 6, lane = t & 63;
    int wm = (wave & 1) * 64, wn2 = (wave >> 1) * 64;
    int lrow = lane & 15, quad = lane >> 4;

    f32x4 acc[4][4];
    #pragma unroll
    for (int i = 0; i < 4; i++)
        #pragma unroll
        for (int j = 0; j < 4; j++)
            acc[i][j] = (f32x4){0.f, 0.f, 0.f, 0.f};

    for (int k0 = 0; k0 < K; k0 += 32) {
        __syncthreads();
        {
            uint4 a0 = *(const uint4*)(Ag + k0);
            uint4 a1 = *(const uint4*)(Ag + k0 + 8);
            *(uint4*)&As[arow * 40 + acol] = a0;
            *(uint4*)&As[arow * 40 + acol + 8] = a1;
            if (!TRANSW) {
                uint4 w0 = *(const uint4*)(WgN + k0);
                uint4 w1 = *(const uint4*)(WgN + k0 + 8);
                *(uint4*)&Ws[arow * 40 + acol] = w0;
                *(uint4*)&Ws[arow * 40 + acol + 8] = w1;
            } else {
                const unsigned short* p = WgT + (long long)(k0 + wk) * ldw;
                uint4 w0 = *(const uint4*)(p);
                uint4 w1 = *(const uint4*)(p + 8);
                const unsigned short* s0 = (const unsigned short*)&w0;
                const unsigned short* s1 = (const unsigned short*)&w1;
                #pragma unroll
                for (int j = 0; j < 8; j++) Ws[(wn + j) * 40 + wk] = s0[j];
                #pragma unroll
                for (int j = 0; j < 8; j++) Ws[(wn + 8 + j) * 40 + wk] = s1[j];
            }
        }
        __syncthreads();
        bf16x8 af[4], bf[4];
        #pragma unroll
        for (int i = 0; i < 4; i++)
            af[i] = *(const bf16x8*)&As[(wm + i * 16 + lrow) * 40 + quad * 8];
        #pragma unroll
        for (int j = 0; j < 4; j++)
            bf[j] = *(const bf16x8*)&Ws[(wn2 + j * 16 + lrow) * 40 + quad * 8];
        #pragma unroll
        for (int i = 0; i < 4; i++)
            #pragma unroll
            for (int j = 0; j < 4; j++)
                acc[i][j] = __builtin_amdgcn_mfma_f32_16x16x32_bf16(af[i], bf[j], acc[i][j], 0, 0, 0);
    }

    #pragma unroll
    for (int i = 0; i < 4; i++) {
        #pragma unroll
        for (int j = 0; j < 4; j++) {
            #pragma unroll
            for (int r = 0; r < 4; r++) {
                int row = m0 + wm + i * 16 + quad * 4 + r;
                int col = n0 + wn2 + j * 16 + lrow;
                float v = acc[i][j][r] * alpha;
                if (BIAS) v += bias[col];
                if (RELU) v = fmaxf(v, 0.f);
                long long idx = cOff + (long long)row * ldc + col;
                if (OUTBF16) ((unsigned short*)Cv)[idx] = f2bf(v);
                else         ((float*)Cv)[idx] = v;
            }
        }
    }
}

// ---------------------------------------------------------------------------
__global__ void cvt_k(const float* __restrict__ in, unsigned short* __restrict__ out, int n)
{
    int i = blockIdx.x * 256 + threadIdx.x;
    int stride = gridDim.x * 256;
    for (; i < n; i += stride) out[i] = f2bf(in[i]);
}

// ---------------------------------------------------------------------------
// GARCH: per-batch variance + 511-step scalar recurrence. 1 block, lane = batch.
// ---------------------------------------------------------------------------
__global__ __launch_bounds__(64) void garch_k(
    const float* __restrict__ xe, const float* __restrict__ omega,
    const float* __restrict__ alpha, const float* __restrict__ beta,
    float* __restrict__ vol)
{
    int b = threadIdx.x;
    float sm = 0.f, sq = 0.f;
    for (int t2 = 0; t2 < TT; t2++) {
        float r = xe[((long long)b * TT + t2) * EE + 5];
        sm += r; sq += r * r;
    }
    float mean = sm / 512.f;
    float var = (sq - 512.f * mean * mean) / 511.f;
    float h = var + 1e-6f;
    float om = log1pf(expf(omega[0]));
    float al = 0.2f / (1.f + expf(-alpha[0]));
    float be = 0.8f / (1.f + expf(-beta[0]));
    for (int t2 = 0; t2 < TT - 1; t2++) {
        float r = xe[((long long)b * TT + t2) * EE + 5];
        h = om + al * r * r + be * h;
    }
    vol[b] = sqrtf(h);
}

// ---------------------------------------------------------------------------
// LSTM step: 256 blocks x 256 threads (no inter-block deps inside a launch —
// global sync comes from the launch boundary; hang-proof by construction).
// Block owns dims d = 2*blk + dl (dl = wave>>1); kh = wave&1 splits K into
// halves; lane = batch. Partials combined via LDS. h/c transposed hT[d][b].
// Weight slice per block = 16 KB -> L1-resident; h read = 32 MB/step from L2.
// ---------------------------------------------------------------------------
__global__ __launch_bounds__(256) void lstm_step2_k(
    const float* __restrict__ xe, const float* __restrict__ w_hh,
    const float* __restrict__ w_ih, const float* __restrict__ b_ih,
    const float* __restrict__ b_hh,
    const float* __restrict__ hin, float* __restrict__ hout,
    float* __restrict__ cbuf, float* __restrict__ xT, int t)
{
    int blk = blockIdx.x;
    int tid = threadIdx.x;
    int wave = tid >> 6, lane = tid & 63;
    int dl = wave >> 1;      // 0..1
    int kh = wave & 1;       // 0..1
    int d = blk * 2 + dl;    // 0..511

    __shared__ float part[2][4][64];

    const float* wbase = w_hh + (long long)d * 512 + kh * 256;
    const float* hp = hin + kh * 256 * 64 + lane;

    float a0 = 0.f, a1 = 0.f, a2 = 0.f, a3 = 0.f;
    #pragma unroll 8
    for (int k = 0; k < 256; k++) {
        float hv = hp[k * 64];
        a0 += hv * wbase[k];
        a1 += hv * wbase[262144 + k];
        a2 += hv * wbase[524288 + k];
        a3 += hv * wbase[786432 + k];
    }
    if (kh == 1) {
        part[dl][0][lane] = a0; part[dl][1][lane] = a1;
        part[dl][2][lane] = a2; part[dl][3][lane] = a3;
    }
    __syncthreads();
    if (kh == 0) {
        a0 += part[dl][0][lane]; a1 += part[dl][1][lane];
        a2 += part[dl][2][lane]; a3 += part[dl][3][lane];
        const float* xr = xe + ((long long)lane * TT + t) * EE;
        float x0 = xr[0], x1 = xr[1], x2 = xr[2], x3 = xr[3], x4 = xr[4], x5 = xr[5];
#define XDOT(r_) (x0*w_ih[(r_)*6+0] + x1*w_ih[(r_)*6+1] + x2*w_ih[(r_)*6+2] + \
                  x3*w_ih[(r_)*6+3] + x4*w_ih[(r_)*6+4] + x5*w_ih[(r_)*6+5])
        float pi = a0 + XDOT(d)        + b_ih[d]        + b_hh[d];
        float pf = a1 + XDOT(512 + d)  + b_ih[512 + d]  + b_hh[512 + d];
        float pg = a2 + XDOT(1024 + d) + b_ih[1024 + d] + b_hh[1024 + d];
        float po = a3 + XDOT(1536 + d) + b_ih[1536 + d] + b_hh[1536 + d];
#undef XDOT
        float ig = 1.f / (1.f + __expf(-pi));
        float fg = 1.f / (1.f + __expf(-pf));
        float gg = tanhf(pg);
        float og = 1.f / (1.f + __expf(-po));
        float c = cbuf[d * 64 + lane];
        float cn = fg * c + ig * gg;
        float hn = og * tanhf(cn);
        cbuf[d * 64 + lane] = cn;
        hout[d * 64 + lane] = hn;
        xT[((long long)t * 512 + d) * 64 + lane] = hn;
    }
}

// ---------------------------------------------------------------------------
// Transpose xT[t][d][b] -> XB[b][t][d] bf16
// ---------------------------------------------------------------------------
__global__ __launch_bounds__(256) void transpose_k(
    const float* __restrict__ xT, unsigned short* __restrict__ XB_)
{
    __shared__ float tile[64][65];
    int dc = blockIdx.x, t = blockIdx.y;
    int tid = threadIdx.x;
    int bcol = tid & 63, grp = tid >> 6;
    #pragma unroll
    for (int j = 0; j < 16; j++) {
        int i = grp * 16 + j;
        tile[i][bcol] = xT[((long long)t * 512 + dc * 64 + i) * 64 + bcol];
    }
    __syncthreads();
    #pragma unroll
    for (int j = 0; j < 16; j++) {
        int brow = grp * 16 + j;
        float v = tile[bcol][brow];
        long long idx = ((long long)brow * TT + t) * DD + dc * 64 + bcol;
        XB_[idx] = f2bf(v);
    }
}

// ---------------------------------------------------------------------------
// Softmax over last dim (512), in-place on bf16 scores. One wave per row.
// ---------------------------------------------------------------------------
__global__ __launch_bounds__(256) void softmax_k(unsigned short* __restrict__ S)
{
    long long row = (long long)blockIdx.x * 4 + (threadIdx.x >> 6);
    int lane = threadIdx.x & 63;
    unsigned short* p = S + row * 512 + lane * 8;
    uint4 raw = *(const uint4*)p;
    unsigned short* u = (unsigned short*)&raw;
    float v[8];
    float m = -1e30f;
    #pragma unroll
    for (int j = 0; j < 8; j++) { v[j] = bf2f(u[j]); m = fmaxf(m, v[j]); }
    #pragma unroll
    for (int off = 1; off < 64; off <<= 1) m = fmaxf(m, __shfl_xor(m, off));
    float s = 0.f;
    #pragma unroll
    for (int j = 0; j < 8; j++) { v[j] = __expf(v[j] - m); s += v[j]; }
    #pragma unroll
    for (int off = 1; off < 64; off <<= 1) s += __shfl_xor(s, off);
    float inv = 1.f / s;
    unsigned int pk[4];
    #pragma unroll
    for (int j = 0; j < 4; j++)
        pk[j] = (unsigned int)f2bf(v[2 * j] * inv) | ((unsigned int)f2bf(v[2 * j + 1] * inv) << 16);
    *(uint4*)p = make_uint4(pk[0], pk[1], pk[2], pk[3]);
}

// ---------------------------------------------------------------------------
// Residual + LayerNorm: XB = LN(XB + Y)*g + b  (bf16 residual stream).
// ---------------------------------------------------------------------------
__global__ __launch_bounds__(256) void ln_k(
    unsigned short* XB_, const float* __restrict__ Y_,
    const float* __restrict__ g, const float* __restrict__ b2)
{
    long long row = (long long)blockIdx.x * 4 + (threadIdx.x >> 6);
    int lane = threadIdx.x & 63;
    long long base = row * 512 + lane * 8;
    float s[8];
    {
        uint4 xr = *(const uint4*)&XB_[base];
        const unsigned short* xu = (const unsigned short*)&xr;
        float4 y0 = *(const float4*)&Y_[base];
        float4 y1 = *(const float4*)&Y_[base + 4];
        s[0] = bf2f(xu[0]) + y0.x; s[1] = bf2f(xu[1]) + y0.y;
        s[2] = bf2f(xu[2]) + y0.z; s[3] = bf2f(xu[3]) + y0.w;
        s[4] = bf2f(xu[4]) + y1.x; s[5] = bf2f(xu[5]) + y1.y;
        s[6] = bf2f(xu[6]) + y1.z; s[7] = bf2f(xu[7]) + y1.w;
    }
    float sm = 0.f, sq = 0.f;
    #pragma unroll
    for (int j = 0; j < 8; j++) { sm += s[j]; sq += s[j] * s[j]; }
    #pragma unroll
    for (int off = 1; off < 64; off <<= 1) {
        sm += __shfl_xor(sm, off);
        sq += __shfl_xor(sq, off);
    }
    float mean = sm * (1.f / 512.f);
    float var = sq * (1.f / 512.f) - mean * mean;
    float rstd = rsqrtf(var + 1e-5f);
    int col = lane * 8;
    float o[8];
    #pragma unroll
    for (int j = 0; j < 8; j++) o[j] = (s[j] - mean) * rstd * g[col + j] + b2[col + j];
    unsigned int pk[4];
    #pragma unroll
    for (int j = 0; j < 4; j++)
        pk[j] = (unsigned int)f2bf(o[2 * j]) | ((unsigned int)f2bf(o[2 * j + 1]) << 16);
    *(uint4*)&XB_[base] = make_uint4(pk[0], pk[1], pk[2], pk[3]);
}

// ---------------------------------------------------------------------------
// Heads: garch_base + gate * ai_residual. One block per batch.
// ---------------------------------------------------------------------------
__global__ __launch_bounds__(128) void head_k(
    const unsigned short* __restrict__ XB_, const float* __restrict__ xe,
    const float* __restrict__ vol,
    const float* __restrict__ rh_w, const float* __restrict__ rh_b,
    const float* __restrict__ g1_w, const float* __restrict__ g1_b,
    const float* __restrict__ g2_w, const float* __restrict__ g2_b,
    const float* __restrict__ gp_w, const float* __restrict__ gp_b,
    float* __restrict__ out)
{
    int b = blockIdx.x, t = threadIdx.x;
    __shared__ float xl[512];
    __shared__ float hid[256];
    for (int j = t; j < 512; j += 128)
        xl[j] = bf2f(XB_[((long long)b * TT + (TT - 1)) * DD + j]);
    float gin[7];
    #pragma unroll
    for (int e = 0; e < 6; e++) gin[e] = xe[((long long)b * TT + (TT - 1)) * EE + e];
    gin[6] = vol[b];
    for (int j = t; j < 256; j += 128) {
        float s = g1_b[j];
        #pragma unroll
        for (int e = 0; e < 7; e++) s += g1_w[j * 7 + e] * gin[e];
        hid[j] = fmaxf(s, 0.f);
    }
    __syncthreads();
    for (int p = t; p < 96; p += 128) {
        float ai = rh_b[p];
        for (int j = 0; j < 512; j++) ai += xl[j] * rh_w[p * 512 + j];
        float gs = g2_b[p];
        for (int j = 0; j < 256; j++) gs += hid[j] * g2_w[p * 256 + j];
        float gate = 1.f / (1.f + expf(-gs));
        out[b * PP + p] = vol[b] * gp_w[p] + gp_b[p] + gate * ai;
    }
}

// ---------------------------------------------------------------------------
// Launch.  Workspace layout (bytes, total ~147.2 MB):
//   XB   bf16 residual  @ 0           (33554432)
//   Y    fp32 branch    @ 33554432    (67108864)   [aliases LSTM xT]
//   CH   chunk region   @ 100663296   (33554432)
//        QKVc @ +0 | SCc @ +12582912 | CTXc @ +29360128 ; HIDc @ +0 [FFN]
//   WB   bf16 weights   @ 134217728   (12582912)
//   HT0/HT1/CT          @ 146800640   (3 x 131072)
//   VOL                 @ 147193856   (256)
// ---------------------------------------------------------------------------
extern "C" void kernel_launch(void* const* d_in, const int* in_sizes, int n_in,
                              void* d_out, int out_size, void* d_ws, size_t ws_size,
                              hipStream_t stream)
{
    const float* x_enc      = (const float*)d_in[0];
    const float* omega      = (const float*)d_in[4];
    const float* alpha      = (const float*)d_in[5];
    const float* beta       = (const float*)d_in[6];
    const float* gp_w       = (const float*)d_in[7];
    const float* gp_b       = (const float*)d_in[8];
    const float* w_ih       = (const float*)d_in[9];
    const float* w_hh       = (const float*)d_in[10];
    const float* b_ih       = (const float*)d_in[11];
    const float* b_hh       = (const float*)d_in[12];
    const float* attn_in_w  = (const float*)d_in[13];
    const float* attn_in_b  = (const float*)d_in[14];
    const float* attn_out_w = (const float*)d_in[15];
    const float* attn_out_b = (const float*)d_in[16];
    const float* ln1_g      = (const float*)d_in[17];
    const float* ln1_b      = (const float*)d_in[18];
    const float* ffn_w1     = (const float*)d_in[19];
    const float* ffn_b1     = (const float*)d_in[20];
    const float* ffn_w2     = (const float*)d_in[21];
    const float* ffn_b2     = (const float*)d_in[22];
    const float* ln2_g      = (const float*)d_in[23];
    const float* ln2_b      = (const float*)d_in[24];
    const float* rh_w       = (const float*)d_in[25];
    const float* rh_b       = (const float*)d_in[26];
    const float* g1_w       = (const float*)d_in[27];
    const float* g1_b       = (const float*)d_in[28];
    const float* g2_w       = (const float*)d_in[29];
    const float* g2_b       = (const float*)d_in[30];

    char* ws = (char*)d_ws;
    unsigned short* XB   = (unsigned short*)(ws + 0);
    float*          Y    = (float*)(ws + 33554432LL);
    float*          XT   = Y;
    unsigned short* QKVc = (unsigned short*)(ws + 100663296LL);
    unsigned short* SCc  = (unsigned short*)(ws + 113246208LL);
    unsigned short* CTXc = (unsigned short*)(ws + 130023424LL);
    unsigned short* HIDc = (unsigned short*)(ws + 100663296LL);
    unsigned short* WATI = (unsigned short*)(ws + 134217728LL);
    unsigned short* WATO = WATI + 1572864;
    unsigned short* WF1  = WATI + 2097152;
    unsigned short* WF2  = WATI + 4194304;
    float*          HT0  = (float*)(ws + 146800640LL);
    float*          HT1  = (float*)(ws + 146931712LL);
    float*          CT   = (float*)(ws + 147062784LL);
    float*          VOL  = (float*)(ws + 147193856LL);

    hipMemsetAsync(HT0, 0, 131072, stream);
    hipMemsetAsync(CT, 0, 131072, stream);

    cvt_k<<<2048, 256, 0, stream>>>(attn_in_w,  WATI, 1572864);
    cvt_k<<<1024, 256, 0, stream>>>(attn_out_w, WATO, 524288);
    cvt_k<<<2048, 256, 0, stream>>>(ffn_w1,     WF1,  2097152);
    cvt_k<<<2048, 256, 0, stream>>>(ffn_w2,     WF2,  2097152);

    garch_k<<<1, 64, 0, stream>>>(x_enc, omega, alpha, beta, VOL);

    for (int t = 0; t < 512; t++) {
        const float* hin = (t & 1) ? HT1 : HT0;
        float* hout      = (t & 1) ? HT0 : HT1;
        lstm_step2_k<<<256, 256, 0, stream>>>(x_enc, w_hh, w_ih, b_ih, b_hh,
                                              hin, hout, CT, XT, t);
    }
    transpose_k<<<dim3(8, 512, 1), 256, 0, stream>>>(XT, XB);

    for (int l = 0; l < 2; l++) {
        // Attention, chunked over batches: 8 chunks x 8 batches (4096 rows)
        for (int c = 0; c < 8; c++) {
            long long rowOff = (long long)c * 8 * 512;
            gemm_bt<false, true, false, true><<<dim3(32, 12, 1), 256, 0, stream>>>(
                XB + rowOff * 512, 512, 0, 0,
                WATI + l * 786432, 512, 0, 0, attn_in_b + l * 1536,
                QKVc, 1536, 0, 0, 512, 1, 1.0f);
            gemm_bt<false, false, false, true><<<dim3(4, 4, 32), 256, 0, stream>>>(
                QKVc, 1536, 786432LL, 128LL, QKVc + 512, 1536, 786432LL, 128LL, nullptr,
                SCc, 512, 1048576LL, 262144LL, 128, 4, 0.088388347648318447f);
            softmax_k<<<4096, 256, 0, stream>>>(SCc);
            gemm_bt<true, false, false, true><<<dim3(4, 1, 32), 256, 0, stream>>>(
                SCc, 512, 1048576LL, 262144LL, QKVc + 1024, 1536, 786432LL, 128LL, nullptr,
                CTXc, 512, 262144LL, 128LL, 512, 4, 1.0f);
            gemm_bt<false, true, false, false><<<dim3(32, 4, 1), 256, 0, stream>>>(
                CTXc, 512, 0, 0, WATO + l * 262144, 512, 0, 0, attn_out_b + l * 512,
                Y + rowOff * 512, 512, 0, 0, 512, 1, 1.0f);
        }
        ln_k<<<8192, 256, 0, stream>>>(XB, Y, ln1_g + l * 512, ln1_b + l * 512);

        // FFN, chunked over rows: 4 chunks x 8192 rows
        for (int mc = 0; mc < 4; mc++) {
            long long rowOff = (long long)mc * 8192;
            gemm_bt<false, true, true, true><<<dim3(64, 16, 1), 256, 0, stream>>>(
                XB + rowOff * 512, 512, 0, 0,
                WF1 + l * 1048576, 512, 0, 0, ffn_b1 + l * 2048,
                HIDc, 2048, 0, 0, 512, 1, 1.0f);
            gemm_bt<false, true, false, false><<<dim3(64, 4, 1), 256, 0, stream>>>(
                HIDc, 2048, 0, 0, WF2 + l * 1048576, 2048, 0, 0, ffn_b2 + l * 512,
                Y + rowOff * 512, 512, 0, 0, 2048, 1, 1.0f);
        }
        ln_k<<<8192, 256, 0, stream>>>(XB, Y, ln2_g + l * 512, ln2_b + l * 512);
    }

    head_k<<<64, 128, 0, stream>>>(XB, x_enc, VOL, rh_w, rh_b,
                                   g1_w, g1_b, g2_w, g2_b, gp_w, gp_b,
                                   (float*)d_out);
}